// Round 17
// baseline (102.806 us; speedup 1.0000x reference)
//
#include <hip/hip_runtime.h>
#include <hip/hip_bf16.h>

#define HID 1024
#define NH 8
#define HD 128
#define BB 2
#define SS 2048
#define CHK 128
#define NCH 16   // SS/CHK

typedef __attribute__((ext_vector_type(8))) short short8;
typedef __attribute__((ext_vector_type(4))) float f32x4;

static __device__ __forceinline__ float b2f(unsigned short u){
  unsigned int x = ((unsigned int)u) << 16; float f;
  __builtin_memcpy(&f, &x, 4); return f;
}
static __device__ __forceinline__ unsigned short f2b(float f){
  unsigned int x; __builtin_memcpy(&x, &f, 4);
  x += 0x7fffu + ((x >> 16) & 1u);
  return (unsigned short)(x >> 16);
}
static __device__ __forceinline__ float head_gamma(int h){
  double lo = -6.238324625039508;   // log(1/512)
  double hi = -3.4657359027997265;  // log(1/32)
  double lin = lo + (hi - lo) * ((double)h / 7.0);
  return (float)(1.0 - exp(lin));
}
static __device__ __forceinline__ f32x4 MFMA(short8 a, short8 b, f32x4 c){
  return __builtin_amdgcn_mfma_f32_16x16x32_bf16(a, b, c, 0, 0, 0);
}

typedef const __attribute__((address_space(1))) unsigned int* gas1_u32p;
typedef __attribute__((address_space(3))) unsigned int* las3_u32p;
static __device__ __forceinline__ void gload_lds16(const void* g, void* l){
  __builtin_amdgcn_global_load_lds((gas1_u32p)g, (las3_u32p)l, 16, 0, 0);
}

// ---------------- qkv weight transposes only ----------------
__global__ __launch_bounds__(256) void k_wqkv(
    const float* __restrict__ Wq, unsigned short* __restrict__ wqT,
    const float* __restrict__ Wk, unsigned short* __restrict__ wkT,
    const float* __restrict__ Wv, unsigned short* __restrict__ wvT)
{
  int bid = blockIdx.x, t = threadIdx.x;   // [0,384)
  __shared__ float tile[32][33];
  int mat = bid >> 7;                      // 0:q 1:k 2:v
  int rem = bid & 127;
  int z = rem >> 4, tl2 = rem & 15;
  const float* ws[3] = { Wq, Wk, Wv };
  unsigned short* os[3] = { wqT, wkT, wvT };
  const float* in = ws[mat] + (size_t)z*HD*HD;
  unsigned short* out = os[mat] + (size_t)z*HD*HD;
  int c0 = (tl2 & 3)*32, r0 = (tl2 >> 2)*32;
  int tx = t & 31, ty = t >> 5;   // 32 x 8
  #pragma unroll
  for (int i=0;i<4;i++) tile[ty+i*8][tx] = in[(size_t)(r0+ty+i*8)*HD + c0+tx];
  __syncthreads();
  #pragma unroll
  for (int i=0;i<4;i++) out[(size_t)(c0+ty+i*8)*HD + r0+tx] = f2b(tile[tx][ty+i*8]);
}

// ---------------- qkv projection + x convert + all transposes (64 tokens per block) -----
__global__ __launch_bounds__(256) void k_qkv(
    const float* __restrict__ x,               // fp32 [B*S][1024]
    const unsigned short* __restrict__ wqT,    // [H][e=128][d=128]
    const unsigned short* __restrict__ wkT,
    const unsigned short* __restrict__ wvT,
    unsigned short* __restrict__ xb,           // bf16 [B*S][1024] (this block's slice)
    unsigned short* __restrict__ qb,
    unsigned short* __restrict__ kb,
    unsigned short* __restrict__ ktsb,
    unsigned short* __restrict__ vtb)
{
  int bid = blockIdx.x;            // (b*8+h)*32 + stile
  int stile = bid & 31;
  int bh = bid >> 5;
  int h = bh & 7, b = bh >> 3;
  int T0 = stile*64;
  int chunk = stile >> 1, pm0 = (stile & 1)*64;
  float l2g = log2f(head_gamma(h));
  __shared__ unsigned short tl[128*72];
  int t = threadIdx.x, wv = t>>6, l = t&63, lr = l&15, lg = l>>4;
  int row0 = T0 + wv*16;
  short8 a[4];
  const float* xp = x + (size_t)(b*SS + row0 + lr)*HID + h*HD + lg*8;
  unsigned short* xbw = xb + (size_t)(b*SS + row0 + lr)*HID + h*HD + lg*8;
  #pragma unroll
  for (int kk=0;kk<4;kk++){
    float4 v0 = *(const float4*)(xp + kk*32);
    float4 v1 = *(const float4*)(xp + kk*32 + 4);
    unsigned short tmp[8] = { f2b(v0.x), f2b(v0.y), f2b(v0.z), f2b(v0.w),
                              f2b(v1.x), f2b(v1.y), f2b(v1.z), f2b(v1.w) };
    a[kk] = *(const short8*)tmp;
    *(short8*)(xbw + kk*32) = a[kk];
  }
  size_t obase = ((size_t)bh*SS + row0)*HD;
  size_t tbase = ((size_t)(bh*NCH + chunk))*HD*CHK + pm0;

  auto wout = [&](unsigned short* dst){
    int e = t & 127, th = t >> 7;
    const uint4* src = (const uint4*)(tl + e*72 + th*32);
    uint4* d4 = (uint4*)(dst + (size_t)e*CHK + th*32);
    #pragma unroll
    for (int i=0;i<4;i++) d4[i] = src[i];
  };

  // ---- q ----
  {
    const unsigned short* wb = wqT + (size_t)h*HD*HD;
    unsigned short* op = qb + obase;
    #pragma unroll
    for (int nt=0;nt<8;nt++){
      f32x4 acc = {0.f,0.f,0.f,0.f};
      #pragma unroll
      for (int kk=0;kk<4;kk++){
        short8 bfr = *(const short8*)(wb + (size_t)(nt*16+lr)*HD + kk*32 + lg*8);
        acc = MFMA(a[kk], bfr, acc);
      }
      #pragma unroll
      for (int r=0;r<4;r++)
        op[(size_t)(lg*4+r)*HD + nt*16 + lr] = f2b(acc[r]);
    }
  }
  // ---- k (row-major store + transposed/scaled stash) ----
  {
    const unsigned short* wb = wkT + (size_t)h*HD*HD;
    unsigned short* op = kb + obase;
    float ksc[4];
    #pragma unroll
    for (int r=0;r<4;r++)
      ksc[r] = exp2f((float)(127 - (pm0 + wv*16 + lg*4 + r))*l2g);
    #pragma unroll
    for (int nt=0;nt<8;nt++){
      f32x4 acc = {0.f,0.f,0.f,0.f};
      #pragma unroll
      for (int kk=0;kk<4;kk++){
        short8 bfr = *(const short8*)(wb + (size_t)(nt*16+lr)*HD + kk*32 + lg*8);
        acc = MFMA(a[kk], bfr, acc);
      }
      #pragma unroll
      for (int r=0;r<4;r++){
        op[(size_t)(lg*4+r)*HD + nt*16 + lr] = f2b(acc[r]);
        tl[(nt*16+lr)*72 + wv*16 + lg*4 + r] = f2b(acc[r]*ksc[r]);
      }
    }
  }
  __syncthreads();
  wout(ktsb + tbase);
  __syncthreads();
  // ---- v (transposed only) ----
  {
    const unsigned short* wb = wvT + (size_t)h*HD*HD;
    #pragma unroll
    for (int nt=0;nt<8;nt++){
      f32x4 acc = {0.f,0.f,0.f,0.f};
      #pragma unroll
      for (int kk=0;kk<4;kk++){
        short8 bfr = *(const short8*)(wb + (size_t)(nt*16+lr)*HD + kk*32 + lg*8);
        acc = MFMA(a[kk], bfr, acc);
      }
      #pragma unroll
      for (int r=0;r<4;r++)
        tl[(nt*16+lr)*72 + wv*16 + lg*4 + r] = f2b(acc[r]);
    }
  }
  __syncthreads();
  wout(vtb + tbase);
}

// ---------------- fused chunk-summary+scan  PLUS  W1/W2 transposes (packed launch) ------
__global__ __launch_bounds__(256) void k_sumscanW(
    const unsigned short* __restrict__ ktsb,  // [bh][16][d][m]
    const unsigned short* __restrict__ vtb,   // [bh][16][e][m]
    unsigned short* __restrict__ ST,          // [bh][16][e][d]
    const float* __restrict__ W1, unsigned short* __restrict__ w1T,
    const float* __restrict__ W2, unsigned short* __restrict__ w2T)
{
  __shared__ float tile[32][33];
  int bid = blockIdx.x, t = threadIdx.x;
  if (bid >= 256){
    int local = bid - 256;                   // [0,2048)
    int which = local >> 10;                 // 0: W1, 1: W2
    int inner = local & 1023;
    const float* in = which ? W2 : W1;
    unsigned short* out = which ? w2T : w1T;
    int c0 = (inner & 31)*32, r0 = (inner >> 5)*32;
    int tx = t & 31, ty = t >> 5;   // 32 x 8
    #pragma unroll
    for (int i=0;i<4;i++) tile[ty+i*8][tx] = in[(size_t)(r0+ty+i*8)*HID + c0+tx];
    __syncthreads();
    #pragma unroll
    for (int i=0;i<4;i++) out[(size_t)(c0+ty+i*8)*HID + r0+tx] = f2b(tile[tx][ty+i*8]);
    return;
  }
  // sumscan: bid = bh*16 + et*2 + dh
  int dh = bid & 1, et = (bid >> 1) & 7, bh = bid >> 4;
  int h = bh & 7;
  float d128 = exp2f(128.f * log2f(head_gamma(h)));
  int wv = t>>6, l = t&63, lr = l&15, lg = l>>4;
  int e0 = et*16;
  int d0w = dh*64 + wv*16;
  const unsigned short* vt = vtb  + (size_t)bh*NCH*HD*CHK;
  const unsigned short* kt = ktsb + (size_t)bh*NCH*HD*CHK;
  unsigned short* Sb = ST + (size_t)bh*NCH*HD*HD;

  f32x4 s = {0.f,0.f,0.f,0.f};
  #pragma unroll
  for (int c=0;c<NCH;c++){
    const unsigned short* vc = vt + (size_t)c*HD*CHK;
    const unsigned short* kc = kt + (size_t)c*HD*CHK;
    f32x4 acc = {0.f,0.f,0.f,0.f};
    #pragma unroll
    for (int kk=0;kk<4;kk++){
      short8 af = *(const short8*)(vc + (size_t)(e0+lr)*CHK + kk*32 + lg*8);
      short8 bf = *(const short8*)(kc + (size_t)(d0w+lr)*CHK + kk*32 + lg*8);
      acc = MFMA(af, bf, acc);
    }
    unsigned short* So = Sb + (size_t)c*HD*HD;
    #pragma unroll
    for (int r=0;r<4;r++){
      So[(size_t)(e0+lg*4+r)*HD + d0w + lr] = f2b(s[r]);
      s[r] = s[r]*d128 + acc[r];
    }
  }
}

// ---------------- FUSED gemm1 + retention + GroupNorm + swish-add (R12 + gpow table) ----
__global__ __launch_bounds__(512) void k_g1ret(
    const unsigned short* __restrict__ A,    // xb [M][K]
    const unsigned short* __restrict__ BT,   // w1T [N][K]
    const unsigned short* __restrict__ qb,
    const unsigned short* __restrict__ kb,
    const unsigned short* __restrict__ vtb,  // [bh][16][e][m]
    const unsigned short* __restrict__ ST,   // [bh][16][e][d]
    const float* __restrict__ gnw,
    const float* __restrict__ gnb,
    unsigned short* __restrict__ Cb,         // opb [M][N]
    int M, int N, int K)
{
  __shared__ unsigned short lsu[65536];      // 128 KiB: 4 gemm bufs | post: sc/S,v,k,ct
  __shared__ float gpowS[128];               // gamma^i table
  const int nb = N >> 7;                     // 8
  const int nwg = (M >> 7) * nb;             // 256
  const int cpx = nwg >> 3;
  int bid0 = blockIdx.x;
  int bid = (bid0 & 7)*cpx + (bid0 >> 3);    // bijective XCD swizzle
  const int m0 = (bid / nb) << 7;
  const int n0 = (bid % nb) << 7;
  const int t = threadIdx.x, wv = t>>6, l = t&63, lr = l&15, lg = l>>4;
  const int wr = (wv>>1)<<5;     // 0,32,64,96
  const int wc = (wv&1)<<6;      // 0,64
  const int srow = l >> 3;                   // 0..7
  const int sgc  = ((l & 7) ^ srow) << 3;    // pre-swizzled source col (shorts)
  const unsigned short* Abase = A  + (size_t)(m0 + wv*16 + srow)*K + sgc;
  const unsigned short* Bbase = BT + (size_t)(n0 + wv*16 + srow)*K + sgc;

  auto stage = [&](int buf, int kt){
    unsigned short* la = lsu + buf*16384;
    unsigned short* lb = la + 8192;
    int k0 = kt << 6;
    #pragma unroll
    for (int it=0; it<2; ++it){
      gload_lds16(Abase + (size_t)(it*8)*K + k0, la + (wv*16 + it*8)*64);
      gload_lds16(Bbase + (size_t)(it*8)*K + k0, lb + (wv*16 + it*8)*64);
    }
  };
  // bulk-stage a 128x128 u16 row-major matrix with XOR-(row&7) block swizzle
  auto stageMat = [&](const unsigned short* g, int reg){
    #pragma unroll
    for (int i=0;i<4;i++){
      int c = i*512 + t;
      int row = c >> 4, p = c & 15;
      gload_lds16(g + row*128 + ((p ^ (row & 7)) << 3),
                  lsu + reg + (i*512 + (t & 448))*8);
    }
  };

  // ---- ret operand pointers ----
  const int b = m0 >> 11, j = (m0 >> 7) & 15, h = n0 >> 7;
  const int bh = b*NH + h;
  const int cj = bh*NCH + j;
  float l2g = log2f(head_gamma(h));
  const unsigned short* qc = qb + ((size_t)bh*SS + j*CHK)*HD;
  const unsigned short* kc = kb + ((size_t)bh*SS + j*CHK)*HD;
  const unsigned short* vt = vtb + (size_t)cj*HD*CHK;
  const unsigned short* Sp = ST + (size_t)cj*HD*HD;

  if (t < 128) gpowS[t] = exp2f((float)t * l2g);

  short8 qf[4];
  #pragma unroll
  for (int kk=0;kk<4;kk++)
    qf[kk] = *(const short8*)(qc + (size_t)(wv*16 + lr)*HD + kk*32 + lg*8);

  f32x4 acc[2][4];
  #pragma unroll
  for (int i=0;i<2;i++)
    #pragma unroll
    for (int j2=0;j2<4;j2++) acc[i][j2] = (f32x4){0,0,0,0};

  const int NT = K >> 6;   // 16
  stage(0,0); stage(1,1); stage(2,2);
  for (int kt = 0; kt < NT; ++kt){
    if (kt < NT-2)       asm volatile("s_waitcnt vmcnt(8)" ::: "memory");
    else if (kt == NT-2) asm volatile("s_waitcnt vmcnt(4)" ::: "memory");
    else                 asm volatile("s_waitcnt vmcnt(0)" ::: "memory");
    __builtin_amdgcn_s_barrier();
    __builtin_amdgcn_sched_barrier(0);
    if (kt+3 < NT) stage((kt+3)&3, kt+3);
    if (kt == NT-3) stageMat(Sp, 0);         // S -> buf0 (dead after this barrier)
    if (kt == NT-2) stageMat(vt, 16384);     // v -> buf1
    if (kt == NT-1) stageMat(kc, 32768);     // k -> buf2
    const unsigned short* pa = lsu + (kt&3)*16384;
    const unsigned short* pb = pa + 8192;
    #pragma unroll
    for (int ks=0; ks<2; ++ks){
      short8 af[2], bf[4];
      #pragma unroll
      for (int i=0;i<2;i++){
        int ra = wr + i*16 + lr;
        af[i] = *(const short8*)(pa + ra*64 + ((((ks<<2)+lg) ^ (ra&7))<<3));
      }
      #pragma unroll
      for (int j2=0;j2<4;j2++){
        int rb = wc + j2*16 + lr;
        bf[j2] = *(const short8*)(pb + rb*64 + ((((ks<<2)+lg) ^ (rb&7))<<3));
      }
      #pragma unroll
      for (int i=0;i<2;i++)
        #pragma unroll
        for (int j2=0;j2<4;j2++)
          acc[i][j2] = MFMA(af[i], bf[j2], acc[i][j2]);
    }
  }
  __syncthreads();                           // S,v,k resident; gemm bufs retired

  // ---- Phase B: racc = gamma^{n+1} * (q @ S^T), S from LDS (buf0, swizzled) ----
  f32x4 racc[8];
  #pragma unroll
  for (int nt=0;nt<8;nt++){
    f32x4 aa = {0,0,0,0};
    #pragma unroll
    for (int kk=0;kk<4;kk++){
      short8 bfr = *(const short8*)(lsu + (nt*16+lr)*128 + (((kk*4+lg) ^ (lr&7))<<3));
      aa = MFMA(qf[kk], bfr, aa);
    }
    racc[nt] = aa;
  }
  {
    float g = exp2f(l2g);
    #pragma unroll
    for (int r=0;r<4;r++){
      int n = wv*16 + lg*4 + r;
      float sf = gpowS[n]*g;                 // gamma^{n+1}
      #pragma unroll
      for (int nt=0;nt<8;nt++) racc[nt][r] *= sf;
    }
  }
  __syncthreads();                           // all waves done reading S -> sc may overwrite

  // ---- Phase A: scores from k-LDS (buf2), sc written swizzled over S region ----
  int ntmax = (wv | 1) + 1;                  // 2,2,4,4,6,6,8,8
  for (int nt=0; nt<ntmax; nt++){
    f32x4 a0 = {0,0,0,0};
    #pragma unroll
    for (int kk=0;kk<4;kk++){
      short8 bfr = *(const short8*)(lsu + 32768 + (nt*16+lr)*128 + (((kk*4+lg) ^ (lr&7))<<3));
      a0 = MFMA(qf[kk], bfr, a0);
    }
    int col = nt*16 + lr;
    #pragma unroll
    for (int r=0;r<4;r++){
      int lrow = wv*16 + lg*4 + r;
      float v0 = (col <= lrow) ? a0[r]*gpowS[lrow-col] : 0.f;
      lsu[lrow*128 + (((col>>3) ^ (lrow&7))<<3) + (col&7)] = f2b(v0);
    }
  }

  // ---- stash swish(C) to ct (buf3, swizzled [128][128]) ----
  #pragma unroll
  for (int i=0;i<2;i++){
    #pragma unroll
    for (int j2=0;j2<4;j2++){
      #pragma unroll
      for (int r=0;r<4;r++){
        int row = wr + i*16 + lg*4 + r;
        int col = wc + j2*16 + lr;
        float v = acc[i][j2][r];
        lsu[49152 + row*128 + (((col>>3) ^ (row&7))<<3) + (col&7)]
          = f2b(v / (1.f + __expf(-v)));
      }
    }
  }

  // ---- PV: racc += scores @ v (sc own-wave rows; v from LDS buf1, swizzled) ----
  int ksmax = (wv >> 1) + 1;                 // 1,1,2,2,3,3,4,4
  for (int ks=0; ks<ksmax; ks++){
    short8 afr = *(const short8*)(lsu + (wv*16+lr)*128 + (((ks*4+lg) ^ (lr&7))<<3));
    #pragma unroll
    for (int nt=0;nt<8;nt++){
      short8 bfr = *(const short8*)(lsu + 16384 + (nt*16+lr)*128 + (((ks*4+lg) ^ (lr&7))<<3));
      racc[nt] = MFMA(afr, bfr, racc[nt]);
    }
  }
  __syncthreads();                           // ct visible cross-wave

  // ---- GroupNorm + combine with swish(C) from ct, store opb bf16 ----
  unsigned short* op = Cb + (size_t)(m0 + wv*16)*N + n0;
  const float* gw  = gnw + h*HD;
  const float* gbb = gnb + h*HD;
  #pragma unroll
  for (int r=0;r<4;r++){
    float s = 0.f, ss = 0.f;
    #pragma unroll
    for (int nt=0;nt<8;nt++){ float x2 = racc[nt][r]; s += x2; ss += x2*x2; }
    #pragma unroll
    for (int off=1; off<16; off<<=1){
      s  += __shfl_xor(s,  off, 64);
      ss += __shfl_xor(ss, off, 64);
    }
    float mu  = s*(1.f/128.f);
    float var = ss*(1.f/128.f) - mu*mu;
    float rs  = rsqrtf(var + 1e-5f);
    int lrow = lg*4 + r;                     // row within wave band
    int Rr = wv*16 + lrow;
    unsigned short* orow = op + (size_t)lrow*N;
    #pragma unroll
    for (int nt=0;nt<8;nt++){
      int col = nt*16 + lr;
      float rv = (racc[nt][r]-mu)*rs*gw[col] + gbb[col];
      float cv = b2f(lsu[49152 + Rr*128 + (((col>>3) ^ (Rr&7))<<3) + (col&7)]);
      orow[col] = f2b(rv + cv);
    }
  }
}

// ---------------- gemm2 (R6-exact): 128x128 tile, 4-buf counted-vmcnt, fp32 out ----------
__global__ __launch_bounds__(512) void k_gemm2(
    const unsigned short* __restrict__ A,    // [M][K]
    const unsigned short* __restrict__ BT,   // [N][K]
    float* __restrict__ Cf,
    int M, int N, int K)
{
  __shared__ unsigned short ls[4][2][128*64];   // 128 KiB
  const int nb = N >> 7;
  const int nwg = (M >> 7) * nb;
  const int cpx = nwg >> 3;
  int bid0 = blockIdx.x;
  int bid = (bid0 & 7)*cpx + (bid0 >> 3);
  const int m0 = (bid / nb) << 7;
  const int n0 = (bid % nb) << 7;
  const int t = threadIdx.x, wv = t>>6, l = t&63, lr = l&15, lg = l>>4;
  const int wr = (wv>>1)<<5;
  const int wc = (wv&1)<<6;
  const int srow = l >> 3;
  const int sgc  = ((l & 7) ^ srow) << 3;
  const unsigned short* Abase = A  + (size_t)(m0 + wv*16 + srow)*K + sgc;
  const unsigned short* Bbase = BT + (size_t)(n0 + wv*16 + srow)*K + sgc;

  auto stage = [&](int buf, int kt){
    unsigned short* la = &ls[buf][0][0];
    unsigned short* lb = &ls[buf][1][0];
    int k0 = kt << 6;
    #pragma unroll
    for (int it=0; it<2; ++it){
      gload_lds16(Abase + (size_t)(it*8)*K + k0, la + (wv*16 + it*8)*64);
      gload_lds16(Bbase + (size_t)(it*8)*K + k0, lb + (wv*16 + it*8)*64);
    }
  };

  f32x4 acc[2][4];
  #pragma unroll
  for (int i=0;i<2;i++)
    #pragma unroll
    for (int j=0;j<4;j++) acc[i][j] = (f32x4){0,0,0,0};

  const int NT = K >> 6;
  stage(0,0); stage(1,1); stage(2,2);
  for (int kt = 0; kt < NT; ++kt){
    if (kt < NT-2)       asm volatile("s_waitcnt vmcnt(8)" ::: "memory");
    else if (kt == NT-2) asm volatile("s_waitcnt vmcnt(4)" ::: "memory");
    else                 asm volatile("s_waitcnt vmcnt(0)" ::: "memory");
    __builtin_amdgcn_s_barrier();
    __builtin_amdgcn_sched_barrier(0);
    if (kt+3 < NT) stage((kt+3)&3, kt+3);
    const unsigned short* pa = &ls[kt&3][0][0];
    const unsigned short* pb = &ls[kt&3][1][0];
    #pragma unroll
    for (int ks=0; ks<2; ++ks){
      short8 af[2], bf[4];
      #pragma unroll
      for (int i=0;i<2;i++){
        int ra = wr + i*16 + lr;
        af[i] = *(const short8*)(pa + ra*64 + ((((ks<<2)+lg) ^ (ra&7))<<3));
      }
      #pragma unroll
      for (int j=0;j<4;j++){
        int rb = wc + j*16 + lr;
        bf[j] = *(const short8*)(pb + rb*64 + ((((ks<<2)+lg) ^ (rb&7))<<3));
      }
      #pragma unroll
      for (int i=0;i<2;i++)
        #pragma unroll
        for (int j=0;j<4;j++)
          acc[i][j] = MFMA(af[i], bf[j], acc[i][j]);
    }
  }

  #pragma unroll
  for (int i=0;i<2;i++)
    #pragma unroll
    for (int j=0;j<4;j++)
      #pragma unroll
      for (int r=0;r<4;r++){
        int row = m0 + wr + i*16 + lg*4 + r;
        int col = n0 + wc + j*16 + lr;
        Cf[(size_t)row*N + col] = acc[i][j][r];
      }
}

extern "C" void kernel_launch(void* const* d_in, const int* in_sizes, int n_in,
                              void* d_out, int out_size, void* d_ws, size_t ws_size,
                              hipStream_t stream)
{
  (void)in_sizes; (void)n_in; (void)out_size; (void)ws_size;
  const float* x   = (const float*)d_in[0];
  const float* Wq  = (const float*)d_in[1];
  const float* Wk  = (const float*)d_in[2];
  const float* Wv  = (const float*)d_in[3];
  const float* W1  = (const float*)d_in[4];
  const float* W2  = (const float*)d_in[5];
  const float* gnw = (const float*)d_in[6];
  const float* gnb = (const float*)d_in[7];
  float* out = (float*)d_out;

  char* wsp = (char*)d_ws;
  size_t off = 0;
  auto alloc = [&](size_t bytes)->void*{
    off = (off + 255) & ~(size_t)255;
    void* p = wsp + off; off += bytes; return p;
  };
  const size_t NTOK = (size_t)BB*SS;  // 4096
  unsigned short* xb   = (unsigned short*)alloc(NTOK*HID*2);
  unsigned short* w1T  = (unsigned short*)alloc((size_t)HID*HID*2);
  unsigned short* w2T  = (unsigned short*)alloc((size_t)HID*HID*2);
  unsigned short* wqT  = (unsigned short*)alloc((size_t)NH*HD*HD*2);
  unsigned short* wkT  = (unsigned short*)alloc((size_t)NH*HD*HD*2);
  unsigned short* wvT  = (unsigned short*)alloc((size_t)NH*HD*HD*2);
  unsigned short* qb   = (unsigned short*)alloc(NTOK*HID*2);
  unsigned short* kb   = (unsigned short*)alloc(NTOK*HID*2);
  unsigned short* ktsb = (unsigned short*)alloc(NTOK*HID*2);
  unsigned short* vtb  = (unsigned short*)alloc(NTOK*HID*2);
  unsigned short* ST   = (unsigned short*)alloc((size_t)BB*NH*NCH*HD*HD*2);
  unsigned short* opb  = (unsigned short*)alloc(NTOK*HID*2);

  k_wqkv<<<dim3(384), dim3(256), 0, stream>>>(Wq, wqT, Wk, wkT, Wv, wvT);
  k_qkv<<<dim3(BB*NH*32), dim3(256), 0, stream>>>(x, wqT, wkT, wvT, xb, qb, kb, ktsb, vtb);
  k_sumscanW<<<dim3(BB*NH*16 + 2048), dim3(256), 0, stream>>>(ktsb, vtb, ST,
                                                              W1, w1T, W2, w2T);
  k_g1ret<<<dim3(256), dim3(512), 0, stream>>>(xb, w1T, qb, kb, vtb, ST, gnw, gnb,
                                               opb, (int)NTOK, HID, HID);
  k_gemm2<<<dim3(256), dim3(512), 0, stream>>>(opb, w2T, out, (int)NTOK, HID, HID);
}

// Round 18
// 97.851 us; speedup vs baseline: 1.0506x; 1.0506x over previous
//
#include <hip/hip_runtime.h>
#include <hip/hip_bf16.h>

#define HID 1024
#define NH 8
#define HD 128
#define BB 2
#define SS 2048
#define CHK 128
#define NCH 16   // SS/CHK

typedef __attribute__((ext_vector_type(8))) short short8;
typedef __attribute__((ext_vector_type(4))) float f32x4;

static __device__ __forceinline__ float b2f(unsigned short u){
  unsigned int x = ((unsigned int)u) << 16; float f;
  __builtin_memcpy(&f, &x, 4); return f;
}
static __device__ __forceinline__ unsigned short f2b(float f){
  unsigned int x; __builtin_memcpy(&x, &f, 4);
  x += 0x7fffu + ((x >> 16) & 1u);
  return (unsigned short)(x >> 16);
}
static __device__ __forceinline__ float head_gamma(int h){
  double lo = -6.238324625039508;   // log(1/512)
  double hi = -3.4657359027997265;  // log(1/32)
  double lin = lo + (hi - lo) * ((double)h / 7.0);
  return (float)(1.0 - exp(lin));
}
static __device__ __forceinline__ f32x4 MFMA(short8 a, short8 b, f32x4 c){
  return __builtin_amdgcn_mfma_f32_16x16x32_bf16(a, b, c, 0, 0, 0);
}

typedef const __attribute__((address_space(1))) unsigned int* gas1_u32p;
typedef __attribute__((address_space(3))) unsigned int* las3_u32p;
static __device__ __forceinline__ void gload_lds16(const void* g, void* l){
  __builtin_amdgcn_global_load_lds((gas1_u32p)g, (las3_u32p)l, 16, 0, 0);
}

// ---------------- qkv weight transposes only ----------------
__global__ __launch_bounds__(256) void k_wqkv(
    const float* __restrict__ Wq, unsigned short* __restrict__ wqT,
    const float* __restrict__ Wk, unsigned short* __restrict__ wkT,
    const float* __restrict__ Wv, unsigned short* __restrict__ wvT)
{
  int bid = blockIdx.x, t = threadIdx.x;   // [0,384)
  __shared__ float tile[32][33];
  int mat = bid >> 7;                      // 0:q 1:k 2:v
  int rem = bid & 127;
  int z = rem >> 4, tl2 = rem & 15;
  const float* ws[3] = { Wq, Wk, Wv };
  unsigned short* os[3] = { wqT, wkT, wvT };
  const float* in = ws[mat] + (size_t)z*HD*HD;
  unsigned short* out = os[mat] + (size_t)z*HD*HD;
  int c0 = (tl2 & 3)*32, r0 = (tl2 >> 2)*32;
  int tx = t & 31, ty = t >> 5;   // 32 x 8
  #pragma unroll
  for (int i=0;i<4;i++) tile[ty+i*8][tx] = in[(size_t)(r0+ty+i*8)*HD + c0+tx];
  __syncthreads();
  #pragma unroll
  for (int i=0;i<4;i++) out[(size_t)(c0+ty+i*8)*HD + r0+tx] = f2b(tile[tx][ty+i*8]);
}

// ---------------- qkv projection + x convert + all transposes (64 tokens per block) -----
__global__ __launch_bounds__(256) void k_qkv(
    const float* __restrict__ x,               // fp32 [B*S][1024]
    const unsigned short* __restrict__ wqT,    // [H][e=128][d=128]
    const unsigned short* __restrict__ wkT,
    const unsigned short* __restrict__ wvT,
    unsigned short* __restrict__ xb,           // bf16 [B*S][1024] (this block's slice)
    unsigned short* __restrict__ qb,
    unsigned short* __restrict__ kb,
    unsigned short* __restrict__ ktsb,
    unsigned short* __restrict__ vtb)
{
  int bid = blockIdx.x;            // (b*8+h)*32 + stile
  int stile = bid & 31;
  int bh = bid >> 5;
  int h = bh & 7, b = bh >> 3;
  int T0 = stile*64;
  int chunk = stile >> 1, pm0 = (stile & 1)*64;
  float l2g = log2f(head_gamma(h));
  __shared__ unsigned short tl[128*72];
  int t = threadIdx.x, wv = t>>6, l = t&63, lr = l&15, lg = l>>4;
  int row0 = T0 + wv*16;
  short8 a[4];
  const float* xp = x + (size_t)(b*SS + row0 + lr)*HID + h*HD + lg*8;
  unsigned short* xbw = xb + (size_t)(b*SS + row0 + lr)*HID + h*HD + lg*8;
  #pragma unroll
  for (int kk=0;kk<4;kk++){
    float4 v0 = *(const float4*)(xp + kk*32);
    float4 v1 = *(const float4*)(xp + kk*32 + 4);
    unsigned short tmp[8] = { f2b(v0.x), f2b(v0.y), f2b(v0.z), f2b(v0.w),
                              f2b(v1.x), f2b(v1.y), f2b(v1.z), f2b(v1.w) };
    a[kk] = *(const short8*)tmp;
    *(short8*)(xbw + kk*32) = a[kk];
  }
  size_t obase = ((size_t)bh*SS + row0)*HD;
  size_t tbase = ((size_t)(bh*NCH + chunk))*HD*CHK + pm0;

  auto wout = [&](unsigned short* dst){
    int e = t & 127, th = t >> 7;
    const uint4* src = (const uint4*)(tl + e*72 + th*32);
    uint4* d4 = (uint4*)(dst + (size_t)e*CHK + th*32);
    #pragma unroll
    for (int i=0;i<4;i++) d4[i] = src[i];
  };

  // ---- q ----
  {
    const unsigned short* wb = wqT + (size_t)h*HD*HD;
    unsigned short* op = qb + obase;
    #pragma unroll
    for (int nt=0;nt<8;nt++){
      f32x4 acc = {0.f,0.f,0.f,0.f};
      #pragma unroll
      for (int kk=0;kk<4;kk++){
        short8 bfr = *(const short8*)(wb + (size_t)(nt*16+lr)*HD + kk*32 + lg*8);
        acc = MFMA(a[kk], bfr, acc);
      }
      #pragma unroll
      for (int r=0;r<4;r++)
        op[(size_t)(lg*4+r)*HD + nt*16 + lr] = f2b(acc[r]);
    }
  }
  // ---- k (row-major store + transposed/scaled stash) ----
  {
    const unsigned short* wb = wkT + (size_t)h*HD*HD;
    unsigned short* op = kb + obase;
    float ksc[4];
    #pragma unroll
    for (int r=0;r<4;r++)
      ksc[r] = exp2f((float)(127 - (pm0 + wv*16 + lg*4 + r))*l2g);
    #pragma unroll
    for (int nt=0;nt<8;nt++){
      f32x4 acc = {0.f,0.f,0.f,0.f};
      #pragma unroll
      for (int kk=0;kk<4;kk++){
        short8 bfr = *(const short8*)(wb + (size_t)(nt*16+lr)*HD + kk*32 + lg*8);
        acc = MFMA(a[kk], bfr, acc);
      }
      #pragma unroll
      for (int r=0;r<4;r++){
        op[(size_t)(lg*4+r)*HD + nt*16 + lr] = f2b(acc[r]);
        tl[(nt*16+lr)*72 + wv*16 + lg*4 + r] = f2b(acc[r]*ksc[r]);
      }
    }
  }
  __syncthreads();
  wout(ktsb + tbase);
  __syncthreads();
  // ---- v (transposed only) ----
  {
    const unsigned short* wb = wvT + (size_t)h*HD*HD;
    #pragma unroll
    for (int nt=0;nt<8;nt++){
      f32x4 acc = {0.f,0.f,0.f,0.f};
      #pragma unroll
      for (int kk=0;kk<4;kk++){
        short8 bfr = *(const short8*)(wb + (size_t)(nt*16+lr)*HD + kk*32 + lg*8);
        acc = MFMA(a[kk], bfr, acc);
      }
      #pragma unroll
      for (int r=0;r<4;r++)
        tl[(nt*16+lr)*72 + wv*16 + lg*4 + r] = f2b(acc[r]);
    }
  }
  __syncthreads();
  wout(vtb + tbase);
}

// ---------------- fused chunk-summary+scan  PLUS  W1/W2 transposes (packed launch) ------
__global__ __launch_bounds__(256) void k_sumscanW(
    const unsigned short* __restrict__ ktsb,  // [bh][16][d][m]
    const unsigned short* __restrict__ vtb,   // [bh][16][e][m]
    unsigned short* __restrict__ ST,          // [bh][16][e][d]
    const float* __restrict__ W1, unsigned short* __restrict__ w1T,
    const float* __restrict__ W2, unsigned short* __restrict__ w2T)
{
  __shared__ float tile[32][33];
  int bid = blockIdx.x, t = threadIdx.x;
  if (bid >= 256){
    int local = bid - 256;                   // [0,2048)
    int which = local >> 10;                 // 0: W1, 1: W2
    int inner = local & 1023;
    const float* in = which ? W2 : W1;
    unsigned short* out = which ? w2T : w1T;
    int c0 = (inner & 31)*32, r0 = (inner >> 5)*32;
    int tx = t & 31, ty = t >> 5;   // 32 x 8
    #pragma unroll
    for (int i=0;i<4;i++) tile[ty+i*8][tx] = in[(size_t)(r0+ty+i*8)*HID + c0+tx];
    __syncthreads();
    #pragma unroll
    for (int i=0;i<4;i++) out[(size_t)(c0+ty+i*8)*HID + r0+tx] = f2b(tile[tx][ty+i*8]);
    return;
  }
  // sumscan: bid = bh*16 + et*2 + dh
  int dh = bid & 1, et = (bid >> 1) & 7, bh = bid >> 4;
  int h = bh & 7;
  float d128 = exp2f(128.f * log2f(head_gamma(h)));
  int wv = t>>6, l = t&63, lr = l&15, lg = l>>4;
  int e0 = et*16;
  int d0w = dh*64 + wv*16;
  const unsigned short* vt = vtb  + (size_t)bh*NCH*HD*CHK;
  const unsigned short* kt = ktsb + (size_t)bh*NCH*HD*CHK;
  unsigned short* Sb = ST + (size_t)bh*NCH*HD*HD;

  f32x4 s = {0.f,0.f,0.f,0.f};
  #pragma unroll
  for (int c=0;c<NCH;c++){
    const unsigned short* vc = vt + (size_t)c*HD*CHK;
    const unsigned short* kc = kt + (size_t)c*HD*CHK;
    f32x4 acc = {0.f,0.f,0.f,0.f};
    #pragma unroll
    for (int kk=0;kk<4;kk++){
      short8 af = *(const short8*)(vc + (size_t)(e0+lr)*CHK + kk*32 + lg*8);
      short8 bf = *(const short8*)(kc + (size_t)(d0w+lr)*CHK + kk*32 + lg*8);
      acc = MFMA(af, bf, acc);
    }
    unsigned short* So = Sb + (size_t)c*HD*HD;
    #pragma unroll
    for (int r=0;r<4;r++){
      So[(size_t)(e0+lg*4+r)*HD + d0w + lr] = f2b(s[r]);
      s[r] = s[r]*d128 + acc[r];
    }
  }
}

// ---------------- FUSED gemm1 + retention + GroupNorm + swish-add (R12-exact) -----------
__global__ __launch_bounds__(512) void k_g1ret(
    const unsigned short* __restrict__ A,    // xb [M][K]
    const unsigned short* __restrict__ BT,   // w1T [N][K]
    const unsigned short* __restrict__ qb,
    const unsigned short* __restrict__ kb,
    const unsigned short* __restrict__ vtb,  // [bh][16][e][m]
    const unsigned short* __restrict__ ST,   // [bh][16][e][d]
    const float* __restrict__ gnw,
    const float* __restrict__ gnb,
    unsigned short* __restrict__ Cb,         // opb [M][N]
    int M, int N, int K)
{
  __shared__ unsigned short lsu[65536];      // 128 KiB: 4 gemm bufs | post: sc/S,v,k,ct
  const int nb = N >> 7;                     // 8
  const int nwg = (M >> 7) * nb;             // 256
  const int cpx = nwg >> 3;
  int bid0 = blockIdx.x;
  int bid = (bid0 & 7)*cpx + (bid0 >> 3);    // bijective XCD swizzle
  const int m0 = (bid / nb) << 7;
  const int n0 = (bid % nb) << 7;
  const int t = threadIdx.x, wv = t>>6, l = t&63, lr = l&15, lg = l>>4;
  const int wr = (wv>>1)<<5;     // 0,32,64,96
  const int wc = (wv&1)<<6;      // 0,64
  const int srow = l >> 3;                   // 0..7
  const int sgc  = ((l & 7) ^ srow) << 3;    // pre-swizzled source col (shorts)
  const unsigned short* Abase = A  + (size_t)(m0 + wv*16 + srow)*K + sgc;
  const unsigned short* Bbase = BT + (size_t)(n0 + wv*16 + srow)*K + sgc;

  auto stage = [&](int buf, int kt){
    unsigned short* la = lsu + buf*16384;
    unsigned short* lb = la + 8192;
    int k0 = kt << 6;
    #pragma unroll
    for (int it=0; it<2; ++it){
      gload_lds16(Abase + (size_t)(it*8)*K + k0, la + (wv*16 + it*8)*64);
      gload_lds16(Bbase + (size_t)(it*8)*K + k0, lb + (wv*16 + it*8)*64);
    }
  };
  // bulk-stage a 128x128 u16 row-major matrix with XOR-(row&7) block swizzle
  auto stageMat = [&](const unsigned short* g, int reg){
    #pragma unroll
    for (int i=0;i<4;i++){
      int c = i*512 + t;
      int row = c >> 4, p = c & 15;
      gload_lds16(g + row*128 + ((p ^ (row & 7)) << 3),
                  lsu + reg + (i*512 + (t & 448))*8);
    }
  };

  // ---- ret operand pointers ----
  const int b = m0 >> 11, j = (m0 >> 7) & 15, h = n0 >> 7;
  const int bh = b*NH + h;
  const int cj = bh*NCH + j;
  float l2g = log2f(head_gamma(h));
  const unsigned short* qc = qb + ((size_t)bh*SS + j*CHK)*HD;
  const unsigned short* kc = kb + ((size_t)bh*SS + j*CHK)*HD;
  const unsigned short* vt = vtb + (size_t)cj*HD*CHK;
  const unsigned short* Sp = ST + (size_t)cj*HD*HD;

  short8 qf[4];
  #pragma unroll
  for (int kk=0;kk<4;kk++)
    qf[kk] = *(const short8*)(qc + (size_t)(wv*16 + lr)*HD + kk*32 + lg*8);

  f32x4 acc[2][4];
  #pragma unroll
  for (int i=0;i<2;i++)
    #pragma unroll
    for (int j2=0;j2<4;j2++) acc[i][j2] = (f32x4){0,0,0,0};

  const int NT = K >> 6;   // 16
  stage(0,0); stage(1,1); stage(2,2);
  for (int kt = 0; kt < NT; ++kt){
    if (kt < NT-2)       asm volatile("s_waitcnt vmcnt(8)" ::: "memory");
    else if (kt == NT-2) asm volatile("s_waitcnt vmcnt(4)" ::: "memory");
    else                 asm volatile("s_waitcnt vmcnt(0)" ::: "memory");
    __builtin_amdgcn_s_barrier();
    __builtin_amdgcn_sched_barrier(0);
    if (kt+3 < NT) stage((kt+3)&3, kt+3);
    if (kt == NT-3) stageMat(Sp, 0);         // S -> buf0 (dead after this barrier)
    if (kt == NT-2) stageMat(vt, 16384);     // v -> buf1
    if (kt == NT-1) stageMat(kc, 32768);     // k -> buf2
    const unsigned short* pa = lsu + (kt&3)*16384;
    const unsigned short* pb = pa + 8192;
    #pragma unroll
    for (int ks=0; ks<2; ++ks){
      short8 af[2], bf[4];
      #pragma unroll
      for (int i=0;i<2;i++){
        int ra = wr + i*16 + lr;
        af[i] = *(const short8*)(pa + ra*64 + ((((ks<<2)+lg) ^ (ra&7))<<3));
      }
      #pragma unroll
      for (int j2=0;j2<4;j2++){
        int rb = wc + j2*16 + lr;
        bf[j2] = *(const short8*)(pb + rb*64 + ((((ks<<2)+lg) ^ (rb&7))<<3));
      }
      #pragma unroll
      for (int i=0;i<2;i++)
        #pragma unroll
        for (int j2=0;j2<4;j2++)
          acc[i][j2] = MFMA(af[i], bf[j2], acc[i][j2]);
    }
  }
  __syncthreads();                           // S,v,k resident; gemm bufs retired

  // ---- Phase B: racc = gamma^{n+1} * (q @ S^T), S from LDS (buf0, swizzled) ----
  f32x4 racc[8];
  #pragma unroll
  for (int nt=0;nt<8;nt++){
    f32x4 aa = {0,0,0,0};
    #pragma unroll
    for (int kk=0;kk<4;kk++){
      short8 bfr = *(const short8*)(lsu + (nt*16+lr)*128 + (((kk*4+lg) ^ (lr&7))<<3));
      aa = MFMA(qf[kk], bfr, aa);
    }
    racc[nt] = aa;
  }
  #pragma unroll
  for (int r=0;r<4;r++){
    int n = wv*16 + lg*4 + r;
    float sf = exp2f((float)(n+1)*l2g);
    #pragma unroll
    for (int nt=0;nt<8;nt++) racc[nt][r] *= sf;
  }
  __syncthreads();                           // all waves done reading S -> sc may overwrite

  // ---- Phase A: scores from k-LDS (buf2), sc written swizzled over S region ----
  int ntmax = (wv | 1) + 1;                  // 2,2,4,4,6,6,8,8
  for (int nt=0; nt<ntmax; nt++){
    f32x4 a0 = {0,0,0,0};
    #pragma unroll
    for (int kk=0;kk<4;kk++){
      short8 bfr = *(const short8*)(lsu + 32768 + (nt*16+lr)*128 + (((kk*4+lg) ^ (lr&7))<<3));
      a0 = MFMA(qf[kk], bfr, a0);
    }
    int col = nt*16 + lr;
    #pragma unroll
    for (int r=0;r<4;r++){
      int lrow = wv*16 + lg*4 + r;
      float v0 = (col <= lrow) ? a0[r]*exp2f((float)(lrow-col)*l2g) : 0.f;
      lsu[lrow*128 + (((col>>3) ^ (lrow&7))<<3) + (col&7)] = f2b(v0);
    }
  }

  // ---- stash swish(C) to ct (buf3, swizzled [128][128]) ----
  #pragma unroll
  for (int i=0;i<2;i++){
    #pragma unroll
    for (int j2=0;j2<4;j2++){
      #pragma unroll
      for (int r=0;r<4;r++){
        int row = wr + i*16 + lg*4 + r;
        int col = wc + j2*16 + lr;
        float v = acc[i][j2][r];
        lsu[49152 + row*128 + (((col>>3) ^ (row&7))<<3) + (col&7)]
          = f2b(v / (1.f + __expf(-v)));
      }
    }
  }

  // ---- PV: racc += scores @ v (sc own-wave rows; v from LDS buf1, swizzled) ----
  int ksmax = (wv >> 1) + 1;                 // 1,1,2,2,3,3,4,4
  for (int ks=0; ks<ksmax; ks++){
    short8 afr = *(const short8*)(lsu + (wv*16+lr)*128 + (((ks*4+lg) ^ (lr&7))<<3));
    #pragma unroll
    for (int nt=0;nt<8;nt++){
      short8 bfr = *(const short8*)(lsu + 16384 + (nt*16+lr)*128 + (((ks*4+lg) ^ (lr&7))<<3));
      racc[nt] = MFMA(afr, bfr, racc[nt]);
    }
  }
  __syncthreads();                           // ct visible cross-wave

  // ---- GroupNorm + combine with swish(C) from ct, store opb bf16 ----
  unsigned short* op = Cb + (size_t)(m0 + wv*16)*N + n0;
  const float* gw  = gnw + h*HD;
  const float* gbb = gnb + h*HD;
  #pragma unroll
  for (int r=0;r<4;r++){
    float s = 0.f, ss = 0.f;
    #pragma unroll
    for (int nt=0;nt<8;nt++){ float x2 = racc[nt][r]; s += x2; ss += x2*x2; }
    #pragma unroll
    for (int off=1; off<16; off<<=1){
      s  += __shfl_xor(s,  off, 64);
      ss += __shfl_xor(ss, off, 64);
    }
    float mu  = s*(1.f/128.f);
    float var = ss*(1.f/128.f) - mu*mu;
    float rs  = rsqrtf(var + 1e-5f);
    int lrow = lg*4 + r;                     // row within wave band
    int Rr = wv*16 + lrow;
    unsigned short* orow = op + (size_t)lrow*N;
    #pragma unroll
    for (int nt=0;nt<8;nt++){
      int col = nt*16 + lr;
      float rv = (racc[nt][r]-mu)*rs*gw[col] + gbb[col];
      float cv = b2f(lsu[49152 + Rr*128 + (((col>>3) ^ (Rr&7))<<3) + (col&7)]);
      orow[col] = f2b(rv + cv);
    }
  }
}

// ---------------- gemm2 (R6-exact): 128x128 tile, 4-buf counted-vmcnt, fp32 out ----------
__global__ __launch_bounds__(512) void k_gemm2(
    const unsigned short* __restrict__ A,    // [M][K]
    const unsigned short* __restrict__ BT,   // [N][K]
    float* __restrict__ Cf,
    int M, int N, int K)
{
  __shared__ unsigned short ls[4][2][128*64];   // 128 KiB
  const int nb = N >> 7;
  const int nwg = (M >> 7) * nb;
  const int cpx = nwg >> 3;
  int bid0 = blockIdx.x;
  int bid = (bid0 & 7)*cpx + (bid0 >> 3);
  const int m0 = (bid / nb) << 7;
  const int n0 = (bid % nb) << 7;
  const int t = threadIdx.x, wv = t>>6, l = t&63, lr = l&15, lg = l>>4;
  const int wr = (wv>>1)<<5;
  const int wc = (wv&1)<<6;
  const int srow = l >> 3;
  const int sgc  = ((l & 7) ^ srow) << 3;
  const unsigned short* Abase = A  + (size_t)(m0 + wv*16 + srow)*K + sgc;
  const unsigned short* Bbase = BT + (size_t)(n0 + wv*16 + srow)*K + sgc;

  auto stage = [&](int buf, int kt){
    unsigned short* la = &ls[buf][0][0];
    unsigned short* lb = &ls[buf][1][0];
    int k0 = kt << 6;
    #pragma unroll
    for (int it=0; it<2; ++it){
      gload_lds16(Abase + (size_t)(it*8)*K + k0, la + (wv*16 + it*8)*64);
      gload_lds16(Bbase + (size_t)(it*8)*K + k0, lb + (wv*16 + it*8)*64);
    }
  };

  f32x4 acc[2][4];
  #pragma unroll
  for (int i=0;i<2;i++)
    #pragma unroll
    for (int j=0;j<4;j++) acc[i][j] = (f32x4){0,0,0,0};

  const int NT = K >> 6;
  stage(0,0); stage(1,1); stage(2,2);
  for (int kt = 0; kt < NT; ++kt){
    if (kt < NT-2)       asm volatile("s_waitcnt vmcnt(8)" ::: "memory");
    else if (kt == NT-2) asm volatile("s_waitcnt vmcnt(4)" ::: "memory");
    else                 asm volatile("s_waitcnt vmcnt(0)" ::: "memory");
    __builtin_amdgcn_s_barrier();
    __builtin_amdgcn_sched_barrier(0);
    if (kt+3 < NT) stage((kt+3)&3, kt+3);
    const unsigned short* pa = &ls[kt&3][0][0];
    const unsigned short* pb = &ls[kt&3][1][0];
    #pragma unroll
    for (int ks=0; ks<2; ++ks){
      short8 af[2], bf[4];
      #pragma unroll
      for (int i=0;i<2;i++){
        int ra = wr + i*16 + lr;
        af[i] = *(const short8*)(pa + ra*64 + ((((ks<<2)+lg) ^ (ra&7))<<3));
      }
      #pragma unroll
      for (int j=0;j<4;j++){
        int rb = wc + j*16 + lr;
        bf[j] = *(const short8*)(pb + rb*64 + ((((ks<<2)+lg) ^ (rb&7))<<3));
      }
      #pragma unroll
      for (int i=0;i<2;i++)
        #pragma unroll
        for (int j=0;j<4;j++)
          acc[i][j] = MFMA(af[i], bf[j], acc[i][j]);
    }
  }

  #pragma unroll
  for (int i=0;i<2;i++)
    #pragma unroll
    for (int j=0;j<4;j++)
      #pragma unroll
      for (int r=0;r<4;r++){
        int row = m0 + wr + i*16 + lg*4 + r;
        int col = n0 + wc + j*16 + lr;
        Cf[(size_t)row*N + col] = acc[i][j][r];
      }
}

extern "C" void kernel_launch(void* const* d_in, const int* in_sizes, int n_in,
                              void* d_out, int out_size, void* d_ws, size_t ws_size,
                              hipStream_t stream)
{
  (void)in_sizes; (void)n_in; (void)out_size; (void)ws_size;
  const float* x   = (const float*)d_in[0];
  const float* Wq  = (const float*)d_in[1];
  const float* Wk  = (const float*)d_in[2];
  const float* Wv  = (const float*)d_in[3];
  const float* W1  = (const float*)d_in[4];
  const float* W2  = (const float*)d_in[5];
  const float* gnw = (const float*)d_in[6];
  const float* gnb = (const float*)d_in[7];
  float* out = (float*)d_out;

  char* wsp = (char*)d_ws;
  size_t off = 0;
  auto alloc = [&](size_t bytes)->void*{
    off = (off + 255) & ~(size_t)255;
    void* p = wsp + off; off += bytes; return p;
  };
  const size_t NTOK = (size_t)BB*SS;  // 4096
  unsigned short* xb   = (unsigned short*)alloc(NTOK*HID*2);
  unsigned short* w1T  = (unsigned short*)alloc((size_t)HID*HID*2);
  unsigned short* w2T  = (unsigned short*)alloc((size_t)HID*HID*2);
  unsigned short* wqT  = (unsigned short*)alloc((size_t)NH*HD*HD*2);
  unsigned short* wkT  = (unsigned short*)alloc((size_t)NH*HD*HD*2);
  unsigned short* wvT  = (unsigned short*)alloc((size_t)NH*HD*HD*2);
  unsigned short* qb   = (unsigned short*)alloc(NTOK*HID*2);
  unsigned short* kb   = (unsigned short*)alloc(NTOK*HID*2);
  unsigned short* ktsb = (unsigned short*)alloc(NTOK*HID*2);
  unsigned short* vtb  = (unsigned short*)alloc(NTOK*HID*2);
  unsigned short* ST   = (unsigned short*)alloc((size_t)BB*NH*NCH*HD*HD*2);
  unsigned short* opb  = (unsigned short*)alloc(NTOK*HID*2);

  k_wqkv<<<dim3(384), dim3(256), 0, stream>>>(Wq, wqT, Wk, wkT, Wv, wvT);
  k_qkv<<<dim3(BB*NH*32), dim3(256), 0, stream>>>(x, wqT, wkT, wvT, xb, qb, kb, ktsb, vtb);
  k_sumscanW<<<dim3(BB*NH*16 + 2048), dim3(256), 0, stream>>>(ktsb, vtb, ST,
                                                              W1, w1T, W2, w2T);
  k_g1ret<<<dim3(256), dim3(512), 0, stream>>>(xb, w1T, qb, kb, vtb, ST, gnw, gnb,
                                               opb, (int)NTOK, HID, HID);
  k_gemm2<<<dim3(256), dim3(512), 0, stream>>>(opb, w2T, out, (int)NTOK, HID, HID);
}